// Round 12
// baseline (280.279 us; speedup 1.0000x reference)
//
#include <hip/hip_runtime.h>
#include <math.h>

#define B_   16
#define N_   2000
#define F_   128
#define D_   64
#define H_   4
#define OW_  200
#define K_   20
#define BN_  (B_*N_)      // 32000
#define HD_  (H_*D_)      // 256
#define EPS_ 1e-5f
#define NP_  2048         // padded N for cos matrix

// ---------------------------------------------------------------- prep: embT + norms + W2 + wscore + semb + bias2 + stat-zero
__global__ __launch_bounds__(256) void k_prep(const float* __restrict__ emb,
                                              const float* __restrict__ Wlin,
                                              const float* __restrict__ atti,
                                              const float* __restrict__ attj,
                                              const float* __restrict__ attei,
                                              const float* __restrict__ attej,
                                              const float* __restrict__ biasg,
                                              const float* __restrict__ Wff,
                                              const float* __restrict__ bff,
                                              float* __restrict__ nrm,
                                              float* __restrict__ embT,
                                              float* __restrict__ W2,
                                              float* __restrict__ wscore,
                                              float* __restrict__ semb,
                                              float* __restrict__ bias2,
                                              double* __restrict__ S1,
                                              double* __restrict__ SS1,
                                              double* __restrict__ S2,
                                              double* __restrict__ SS2) {
    const int t = threadIdx.x, b = blockIdx.x;
    if (b < 512) {                                // embT transpose + norms
        const int idx = b * 256 + t;
        int k = idx >> 11, j = idx & (NP_ - 1);
        embT[idx] = (j < N_) ? emb[(size_t)j * D_ + k] : 0.f;
        if (b < 8) {
            int i = idx;
            if (i < N_) {
                const float* e = emb + (size_t)i * D_;
                float s = 0.f;
                #pragma unroll
                for (int d = 0; d < D_; ++d) s += e[d] * e[d];
                nrm[i] = sqrtf(s);
            } else if (i < NP_) {
                nrm[i] = 1.f;
            }
        }
    } else if (b < 640) {                         // W2: block -> one f row, t -> col c
        const int f = b - 512;
        const int h = t >> 6, d = t & 63;
        float s = 0.f;
        for (int dd = 0; dd < D_; ++dd)
            s = fmaf(Wlin[(size_t)f * HD_ + h * D_ + dd],
                     Wff[(size_t)(h * D_ + dd) * D_ + d], s);
        W2[(size_t)f * HD_ + t] = s;
    } else if (b < 644) {                         // wscore: 128x8
        const int idx = (b - 640) * 256 + t;      // [0,1024)
        const int f = idx >> 3, c8 = idx & 7;
        const int h = c8 & 3;
        const float* a = (c8 < 4) ? atti : attj;
        float s = 0.f;
        for (int d = 0; d < D_; ++d)
            s = fmaf(Wlin[(size_t)f * HD_ + h * D_ + d], a[h * D_ + d], s);
        wscore[idx] = s;
    } else if (b < 707) {                         // semb: 2000x8
        const int idx = (b - 644) * 256 + t;      // [0,16128)
        const int i = idx >> 3, c8 = idx & 7;
        if (i < N_) {
            const int h = c8 & 3;
            const float* a = (c8 < 4) ? attei : attej;
            float s = 0.f;
            for (int d = 0; d < D_; ++d)
                s = fmaf(emb[(size_t)i * D_ + d], a[h * D_ + d], s);
            semb[idx] = s;
        }
    } else {                                      // bias2 + zero BN stat accumulators
        if (t < D_) {
            float s = bff[t];
            for (int c = 0; c < HD_; ++c)
                s = fmaf(biasg[c], Wff[(size_t)c * D_ + t], s);
            bias2[t] = s;
            S1[t] = 0.0; SS1[t] = 0.0; S2[t] = 0.0; SS2[t] = 0.0;
        }
    }
}

// ---------------------------------------------------------------- cos tile GEMM: 16 rows x 256 cols / block
__global__ __launch_bounds__(256) void k_cos(const float* __restrict__ emb,
                                             const float* __restrict__ embT,
                                             const float* __restrict__ nrm,
                                             float* __restrict__ cosm) {
    const int t    = threadIdx.x;
    const int i0   = blockIdx.y * 16;
    const int r0   = (t >> 6) * 4;
    const int lane = t & 63;
    const int j4   = blockIdx.x * 256 + lane * 4;

    __shared__ float eL[16 * D_];        // 4 KB
    for (int idx = t; idx < 16 * D_; idx += 256)
        eL[idx] = emb[(size_t)i0 * D_ + idx];
    __syncthreads();

    float acc[4][4];
    #pragma unroll
    for (int r = 0; r < 4; ++r)
        #pragma unroll
        for (int cc = 0; cc < 4; ++cc) acc[r][cc] = 0.f;

    for (int k4 = 0; k4 < D_; k4 += 4) {
        float es[4][4];
        #pragma unroll
        for (int r = 0; r < 4; ++r) {
            float4 ev = *(const float4*)&eL[(r0 + r) * D_ + k4];   // wave-uniform broadcast
            es[r][0] = ev.x; es[r][1] = ev.y; es[r][2] = ev.z; es[r][3] = ev.w;
        }
        #pragma unroll
        for (int kk = 0; kk < 4; ++kk) {
            float4 b = *(const float4*)&embT[(size_t)(k4 + kk) * NP_ + j4];  // coalesced
            #pragma unroll
            for (int r = 0; r < 4; ++r) {
                acc[r][0] = fmaf(es[r][kk], b.x, acc[r][0]);
                acc[r][1] = fmaf(es[r][kk], b.y, acc[r][1]);
                acc[r][2] = fmaf(es[r][kk], b.z, acc[r][2]);
                acc[r][3] = fmaf(es[r][kk], b.w, acc[r][3]);
            }
        }
    }

    float4 nj = *(const float4*)&nrm[j4];   // pad lanes read 1.0
    #pragma unroll
    for (int r = 0; r < 4; ++r) {
        float ni = nrm[i0 + r0 + r];
        float4 o;
        o.x = acc[r][0] / (ni * nj.x);      // same formula/order as before
        o.y = acc[r][1] / (ni * nj.y);
        o.z = acc[r][2] / (ni * nj.z);
        o.w = acc[r][3] / (ni * nj.w);
        *(float4*)&cosm[(size_t)(i0 + r0 + r) * NP_ + j4] = o;
    }
}

// ---------------------------------------------------------------- top-k select: one wave per row, packed u64 keys
__device__ __forceinline__ unsigned long long kmax64(unsigned long long a,
                                                     unsigned long long b) {
    return a > b ? a : b;
}

__global__ __launch_bounds__(256) void k_sel(const float* __restrict__ cosm,
                                             int* __restrict__ topk) {
    const int t    = threadIdx.x;
    const int lane = t & 63;
    const int i    = blockIdx.x * 4 + (t >> 6);
    const float* row = cosm + (size_t)i * NP_;

    // slot s -> j = (s>>2)*256 + lane*4 + (s&3)
    unsigned long long key[32];
    #pragma unroll
    for (int m = 0; m < 8; ++m) {
        float4 b = *(const float4*)&row[m * 256 + lane * 4];
        float vv[4] = {b.x, b.y, b.z, b.w};
        #pragma unroll
        for (int q = 0; q < 4; ++q) {
            const int s = m * 4 + q;
            const int j = m * 256 + lane * 4 + q;
            unsigned int x  = __float_as_uint(vv[q]);
            unsigned int mv = (x & 0x80000000u) ? ~x : (x | 0x80000000u);
            unsigned long long kk =
                ((unsigned long long)mv << 32) | (unsigned int)(NP_ - 1 - j);
            key[s] = (j < N_) ? kk : 0ull;   // pad/killed slots: smallest key
        }
    }

    unsigned long long loc;
    {
        unsigned long long l1[16];
        #pragma unroll
        for (int s = 0; s < 16; ++s) l1[s] = kmax64(key[s], key[s + 16]);
        unsigned long long l2[8];
        #pragma unroll
        for (int s = 0; s < 8; ++s) l2[s] = kmax64(l1[s], l1[s + 8]);
        unsigned long long l3[4];
        #pragma unroll
        for (int s = 0; s < 4; ++s) l3[s] = kmax64(l2[s], l2[s + 4]);
        loc = kmax64(kmax64(l3[0], l3[2]), kmax64(l3[1], l3[3]));
    }

    for (int k = 0; k < K_; ++k) {
        unsigned long long w = loc;
        #pragma unroll
        for (int off = 1; off < 64; off <<= 1)
            w = kmax64(w, __shfl_xor(w, off, 64));

        if (lane == 0)
            topk[i * K_ + k] = (NP_ - 1) - (int)(unsigned int)(w & 0xFFFFFFFFu);

        #pragma unroll
        for (int s = 0; s < 32; ++s)
            if (key[s] == w) key[s] = 0ull;
        {
            unsigned long long l1[16];
            #pragma unroll
            for (int s = 0; s < 16; ++s) l1[s] = kmax64(key[s], key[s + 16]);
            unsigned long long l2[8];
            #pragma unroll
            for (int s = 0; s < 8; ++s) l2[s] = kmax64(l1[s], l1[s + 8]);
            unsigned long long l3[4];
            #pragma unroll
            for (int s = 0; s < 4; ++s) l3[s] = kmax64(l2[s], l2[s + 4]);
            loc = kmax64(kmax64(l3[0], l3[2]), kmax64(l3[1], l3[3]));
        }
    }
}

// ---------------------------------------------------------------- k_lin: yh = x@W2 + scores (32 nodes/block)
#define XS_ 132
__global__ __launch_bounds__(256) void k_lin(const float* __restrict__ x,
                                             const float* __restrict__ W2,
                                             const float* __restrict__ wscore,
                                             const float* __restrict__ semb,
                                             float* __restrict__ yh,
                                             float* __restrict__ si,
                                             float* __restrict__ sj) {
    const int t    = threadIdx.x;
    const int n0   = blockIdx.x * 32;     // 1000 blocks
    const int r0   = (t >> 6) * 8;        // wave's 8 rows
    const int lane = t & 63;
    const int c4   = lane * 4;

    __shared__ float xL[32 * XS_];        // 16.9 KB (padded rows)
    __shared__ float wsL[F_ * 8];         // 4 KB

    for (int idx = t; idx < 32 * F_; idx += 256)
        xL[(idx >> 7) * XS_ + (idx & 127)] = x[(size_t)n0 * F_ + idx];
    for (int idx = t; idx < F_ * 8; idx += 256)
        wsL[idx] = wscore[idx];
    __syncthreads();

    float acc[8][4];
    #pragma unroll
    for (int r = 0; r < 8; ++r)
        #pragma unroll
        for (int cc = 0; cc < 4; ++cc) acc[r][cc] = 0.f;

    for (int k4 = 0; k4 < F_; k4 += 4) {
        float xs[8][4];
        #pragma unroll
        for (int r = 0; r < 8; ++r) {
            float4 xv = *(const float4*)&xL[(r0 + r) * XS_ + k4];  // uniform broadcast
            xs[r][0] = xv.x; xs[r][1] = xv.y; xs[r][2] = xv.z; xs[r][3] = xv.w;
        }
        #pragma unroll
        for (int kk = 0; kk < 4; ++kk) {
            float4 w = *(const float4*)&W2[(size_t)(k4 + kk) * HD_ + c4];  // coalesced
            #pragma unroll
            for (int r = 0; r < 8; ++r) {
                acc[r][0] = fmaf(xs[r][kk], w.x, acc[r][0]);
                acc[r][1] = fmaf(xs[r][kk], w.y, acc[r][1]);
                acc[r][2] = fmaf(xs[r][kk], w.z, acc[r][2]);
                acc[r][3] = fmaf(xs[r][kk], w.w, acc[r][3]);
            }
        }
    }

    #pragma unroll
    for (int r = 0; r < 8; ++r) {
        float4 o; o.x = acc[r][0]; o.y = acc[r][1]; o.z = acc[r][2]; o.w = acc[r][3];
        *(float4*)&yh[(size_t)(n0 + r0 + r) * HD_ + c4] = o;
    }

    // scores: 32 rows x 8 (c8: 0-3 = si heads, 4-7 = sj heads) = 256 tasks, 1/thread
    {
        const int row = t >> 3, c8 = t & 7;
        float s = 0.f;
        for (int k4 = 0; k4 < F_; k4 += 4) {
            float4 xv = *(const float4*)&xL[row * XS_ + k4];  // 8 rows -> 8 banks
            s = fmaf(xv.x, wsL[(k4 + 0) * 8 + c8], s);
            s = fmaf(xv.y, wsL[(k4 + 1) * 8 + c8], s);
            s = fmaf(xv.z, wsL[(k4 + 2) * 8 + c8], s);
            s = fmaf(xv.w, wsL[(k4 + 3) * 8 + c8], s);
        }
        const int n = n0 + row;
        const int i = n % N_;
        s += semb[i * 8 + c8];
        if (c8 < 4) si[(size_t)n * H_ + c8]       = s;
        else        sj[(size_t)n * H_ + (c8 - 4)] = s;
    }
}

// ---------------------------------------------------------------- attention: softmax + gather-sum of yh + head-reduce + BN1 stats
#define RA_ 16
__global__ __launch_bounds__(256) void k_attn(const float* __restrict__ yh,
                                              const float* __restrict__ si,
                                              const float* __restrict__ sj,
                                              const int* __restrict__ topk,
                                              const float* __restrict__ bias2,
                                              float* __restrict__ out2,
                                              double* __restrict__ S1,
                                              double* __restrict__ SS1) {
    const int t   = threadIdx.x;
    const int nwg = BN_ / RA_;                            // 2000, %8==0
    const int swz = (blockIdx.x & 7) * (nwg >> 3) + (blockIdx.x >> 3);  // bijective
    const int n0  = swz * RA_;
    __shared__ int   srcL[RA_][21];
    __shared__ float wA[RA_][H_][21];
    __shared__ float oL[RA_][D_];         // staged out2 values for BN1 stats

    for (int idx = t; idx < RA_ * 21; idx += 256) {   // 16 nodes * 21 edges
        const int r = idx / 21, e = idx % 21;
        const int n = n0 + r;
        const int i = n % N_;
        const int b = n / N_;
        int s; bool dead = false;
        if (e < K_) { int kk = topk[i * K_ + e]; s = b * N_ + kk; dead = (kk == i); }
        else        { s = n; }
        srcL[r][e] = s;
        #pragma unroll
        for (int h = 0; h < H_; ++h) {
            float a = si[(size_t)n * H_ + h] + sj[(size_t)s * H_ + h];
            a = a > 0.f ? a : 0.2f * a;   // leaky_relu(0.2)
            if (dead) a = -1e30f;         // removed self-loop (after lrelu, as in ref)
            wA[r][h][e] = a;
        }
    }
    __syncthreads();

    if (t < RA_ * H_) {                   // softmax over 21 edges, per (node, head)
        const int r = t >> 2, h = t & 3;
        float m = -3e38f;
        for (int e = 0; e < 21; ++e) m = fmaxf(m, wA[r][h][e]);
        float sum = 0.f;
        for (int e = 0; e < 21; ++e) { float ex = expf(wA[r][h][e] - m); wA[r][h][e] = ex; sum += ex; }
        float inv = 1.f / (sum + 1e-16f);
        for (int e = 0; e < 21; ++e) wA[r][h][e] *= inv;
    }
    __syncthreads();

    {   // gather-weighted sum of yh rows, then reduce over heads via shfl
        const int g = t >> 6, lane = t & 63, c4 = lane * 4, h = lane >> 4;
        #pragma unroll
        for (int rr = 0; rr < 4; ++rr) {
            const int r = g * 4 + rr;
            float a0 = 0.f, a1 = 0.f, a2 = 0.f, a3 = 0.f;
            for (int e = 0; e < 21; ++e) {
                float wv = wA[r][h][e];
                float4 yv = *(const float4*)&yh[(size_t)srcL[r][e] * HD_ + c4];
                a0 = fmaf(wv, yv.x, a0); a1 = fmaf(wv, yv.y, a1);
                a2 = fmaf(wv, yv.z, a2); a3 = fmaf(wv, yv.w, a3);
            }
            // sum the 4 head-lanes {l, l^16, l^32, l^48}
            a0 += __shfl_xor(a0, 16); a0 += __shfl_xor(a0, 32);
            a1 += __shfl_xor(a1, 16); a1 += __shfl_xor(a1, 32);
            a2 += __shfl_xor(a2, 16); a2 += __shfl_xor(a2, 32);
            a3 += __shfl_xor(a3, 16); a3 += __shfl_xor(a3, 32);
            if (lane < 16) {
                float4 b2 = *(const float4*)&bias2[lane * 4];
                float4 o; o.x = a0 + b2.x; o.y = a1 + b2.y;
                          o.z = a2 + b2.z; o.w = a3 + b2.w;
                *(float4*)&out2[(size_t)(n0 + r) * D_ + lane * 4] = o;
                *(float4*)&oL[r][lane * 4] = o;
            }
        }
    }
    __syncthreads();

    if (t < D_) {                         // BN1 partial stats: channel t over 16 rows
        double s = 0.0, ss = 0.0;
        #pragma unroll
        for (int r = 0; r < RA_; ++r) {
            double v = (double)oL[r][t];
            s += v; ss += v * v;
        }
        atomicAdd(&S1[t], s);
        atomicAdd(&SS1[t], ss);
    }
}

// ---------------------------------------------------------------- BN1 apply + *emb + BN2 stats
__global__ __launch_bounds__(256) void k_bn1(const float* __restrict__ out2,
                                             const float* __restrict__ emb,
                                             const double* __restrict__ S1,
                                             const double* __restrict__ SS1,
                                             const float* __restrict__ g1,
                                             const float* __restrict__ b1,
                                             float* __restrict__ hb,
                                             double* __restrict__ S2,
                                             double* __restrict__ SS2) {
    const int t = threadIdx.x;
    __shared__ float scale[64], shift[64];
    if (t < 64) {
        double mu  = S1[t] / (double)BN_;
        double var = SS1[t] / (double)BN_ - mu * mu;
        float rstd = rsqrtf((float)var + EPS_);
        float sc   = rstd * g1[t];
        scale[t] = sc;
        shift[t] = b1[t] - (float)mu * sc;
    }
    __syncthreads();
    const int d = t & 63;
    double s = 0.0, ss = 0.0;
    const int total = BN_ * D_;
    for (int idx = blockIdx.x * 256 + t; idx < total; idx += gridDim.x * 256) {
        float v = out2[idx];
        v = v * scale[d] + shift[d];
        v = fmaxf(v, 0.f);
        int n = idx >> 6;          // node index
        int i = n % N_;
        v *= emb[(size_t)i * D_ + d];
        hb[idx] = v;
        s += v; ss += (double)v * v;
    }
    __shared__ double sb[256], ssb[256];
    sb[t] = s; ssb[t] = ss;
    __syncthreads();
    if (t < 64) {
        double a = sb[t] + sb[t + 64] + sb[t + 128] + sb[t + 192];
        double b = ssb[t] + ssb[t + 64] + ssb[t + 128] + ssb[t + 192];
        atomicAdd(&S2[t], a);
        atomicAdd(&SS2[t], b);
    }
}

// ---------------------------------------------------------------- BN2 apply + out = h@W_out + b_out (16 nodes/block)
__global__ __launch_bounds__(256) void k_out(const float* __restrict__ hb,
                                             const double* __restrict__ S2,
                                             const double* __restrict__ SS2,
                                             const float* __restrict__ g2,
                                             const float* __restrict__ b2,
                                             const float* __restrict__ Wout,
                                             const float* __restrict__ bout,
                                             float* __restrict__ out) {
    const int t  = threadIdx.x;
    const int n0 = blockIdx.x * 16;
    __shared__ float scale[64], shift[64];
    __shared__ float hL[16 * D_];
    if (t < 64) {
        double mu  = S2[t] / (double)BN_;
        double var = SS2[t] / (double)BN_ - mu * mu;
        float rstd = rsqrtf((float)var + EPS_);
        float sc   = rstd * g2[t];
        scale[t] = sc;
        shift[t] = b2[t] - (float)mu * sc;
    }
    __syncthreads();
    for (int idx = t; idx < 16 * D_; idx += 256) {
        float v = hb[(size_t)n0 * D_ + idx];
        int d = idx & 63;
        v = fmaxf(v * scale[d] + shift[d], 0.f);
        hL[idx] = v;
    }
    __syncthreads();
    if (t < OW_) {
        float acc[16];
        #pragma unroll
        for (int r = 0; r < 16; ++r) acc[r] = 0.f;
        for (int d4 = 0; d4 < D_; d4 += 4) {
            float hs[16][4];
            #pragma unroll
            for (int r = 0; r < 16; ++r) {
                float4 hv = *(const float4*)&hL[r * D_ + d4];   // uniform b128 broadcast
                hs[r][0] = hv.x; hs[r][1] = hv.y; hs[r][2] = hv.z; hs[r][3] = hv.w;
            }
            #pragma unroll
            for (int kk = 0; kk < 4; ++kk) {
                float w = Wout[(size_t)(d4 + kk) * OW_ + t];
                #pragma unroll
                for (int r = 0; r < 16; ++r) acc[r] = fmaf(hs[r][kk], w, acc[r]);
            }
        }
        float bo = bout[t];
        #pragma unroll
        for (int r = 0; r < 16; ++r) out[(size_t)(n0 + r) * OW_ + t] = acc[r] + bo;
    }
}

// ---------------------------------------------------------------- launch
extern "C" void kernel_launch(void* const* d_in, const int* in_sizes, int n_in,
                              void* d_out, int out_size, void* d_ws, size_t ws_size,
                              hipStream_t stream) {
    const float* data  = (const float*)d_in[0];
    const float* emb   = (const float*)d_in[1];
    const float* Wlin  = (const float*)d_in[2];
    const float* atti  = (const float*)d_in[3];
    const float* attj  = (const float*)d_in[4];
    const float* attei = (const float*)d_in[5];
    const float* attej = (const float*)d_in[6];
    const float* biasg = (const float*)d_in[7];
    const float* Wff   = (const float*)d_in[8];
    const float* bff   = (const float*)d_in[9];
    const float* g1    = (const float*)d_in[10];
    const float* b1    = (const float*)d_in[11];
    const float* g2    = (const float*)d_in[12];
    const float* b2    = (const float*)d_in[13];
    const float* Wout  = (const float*)d_in[14];
    const float* bout  = (const float*)d_in[15];
    float* out = (float*)d_out;

    char* w = (char*)d_ws;
    size_t off = 0;
    auto alloc = [&](size_t bytes) -> void* {
        void* p = w + off;
        off += (bytes + 255) & ~(size_t)255;
        return p;
    };
    float*  nrm    = (float*) alloc((size_t)NP_ * sizeof(float));        // padded
    int*    topk   = (int*)   alloc((size_t)N_ * K_ * sizeof(int));
    float*  bias2  = (float*) alloc((size_t)D_ * sizeof(float));
    float*  W2     = (float*) alloc((size_t)F_ * HD_ * sizeof(float));   // 131 KB
    float*  wscore = (float*) alloc((size_t)F_ * 8 * sizeof(float));     // 4 KB
    float*  semb   = (float*) alloc((size_t)N_ * 8 * sizeof(float));     // 64 KB
    // union region: {embT, cosm} live only during topk phase; yh reuses it after
    float*  yh   = (float*) alloc((size_t)BN_ * HD_ * sizeof(float));    // 32.8 MB
    float*  embT = yh;                                                   // 0.5 MB
    float*  cosm = yh + (size_t)D_ * NP_;                                // 16.4 MB
    float*  si   = (float*) alloc((size_t)BN_ * H_ * sizeof(float));
    float*  sj   = (float*) alloc((size_t)BN_ * H_ * sizeof(float));
    float*  out2 = (float*) alloc((size_t)BN_ * D_ * sizeof(float));     // 8.2 MB
    float*  hb   = (float*) alloc((size_t)BN_ * D_ * sizeof(float));     // 8.2 MB
    double* S1   = (double*)alloc(64 * sizeof(double));
    double* SS1  = (double*)alloc(64 * sizeof(double));
    double* S2   = (double*)alloc(64 * sizeof(double));
    double* SS2  = (double*)alloc(64 * sizeof(double));

    hipLaunchKernelGGL(k_prep,  dim3(708),          dim3(256), 0, stream,
                       emb, Wlin, atti, attj, attei, attej, biasg, Wff, bff,
                       nrm, embT, W2, wscore, semb, bias2, S1, SS1, S2, SS2);
    hipLaunchKernelGGL(k_cos,   dim3(NP_/256, N_/16), dim3(256), 0, stream,
                       emb, embT, nrm, cosm);
    hipLaunchKernelGGL(k_sel,   dim3(N_/4),          dim3(256), 0, stream, cosm, topk);
    hipLaunchKernelGGL(k_lin,   dim3(BN_ / 32),      dim3(256), 0, stream,
                       data, W2, wscore, semb, yh, si, sj);
    hipLaunchKernelGGL(k_attn,  dim3(BN_ / RA_),     dim3(256), 0, stream,
                       yh, si, sj, topk, bias2, out2, S1, SS1);
    hipLaunchKernelGGL(k_bn1,   dim3(512),           dim3(256), 0, stream,
                       out2, emb, S1, SS1, g1, b1, hb, S2, SS2);
    hipLaunchKernelGGL(k_out,   dim3(BN_ / 16),      dim3(256), 0, stream,
                       hb, S2, SS2, g2, b2, Wout, bout, out);
}

// Round 13
// 247.742 us; speedup vs baseline: 1.1313x; 1.1313x over previous
//
#include <hip/hip_runtime.h>
#include <math.h>

#define B_   16
#define N_   2000
#define F_   128
#define D_   64
#define H_   4
#define OW_  200
#define K_   20
#define BN_  (B_*N_)      // 32000
#define HD_  (H_*D_)      // 256
#define EPS_ 1e-5f
#define NP_  2048         // padded N for cos matrix
#define NREP_ 16          // BN1-stat accumulator replicas (atomic decontention)

// ---------------------------------------------------------------- prep: embT + norms + W2 + wscore + semb + bias2 + stat-zero
__global__ __launch_bounds__(256) void k_prep(const float* __restrict__ emb,
                                              const float* __restrict__ Wlin,
                                              const float* __restrict__ atti,
                                              const float* __restrict__ attj,
                                              const float* __restrict__ attei,
                                              const float* __restrict__ attej,
                                              const float* __restrict__ biasg,
                                              const float* __restrict__ Wff,
                                              const float* __restrict__ bff,
                                              float* __restrict__ nrm,
                                              float* __restrict__ embT,
                                              float* __restrict__ W2,
                                              float* __restrict__ wscore,
                                              float* __restrict__ semb,
                                              float* __restrict__ bias2,
                                              double* __restrict__ S1R,
                                              double* __restrict__ SS1R,
                                              double* __restrict__ S2,
                                              double* __restrict__ SS2) {
    const int t = threadIdx.x, b = blockIdx.x;
    if (b < 512) {                                // embT transpose + norms
        const int idx = b * 256 + t;
        int k = idx >> 11, j = idx & (NP_ - 1);
        embT[idx] = (j < N_) ? emb[(size_t)j * D_ + k] : 0.f;
        if (b < 8) {
            int i = idx;
            if (i < N_) {
                const float* e = emb + (size_t)i * D_;
                float s = 0.f;
                #pragma unroll
                for (int d = 0; d < D_; ++d) s += e[d] * e[d];
                nrm[i] = sqrtf(s);
            } else if (i < NP_) {
                nrm[i] = 1.f;
            }
        }
    } else if (b < 640) {                         // W2: block -> one f row, t -> col c
        const int f = b - 512;
        const int h = t >> 6, d = t & 63;
        float s = 0.f;
        for (int dd = 0; dd < D_; ++dd)
            s = fmaf(Wlin[(size_t)f * HD_ + h * D_ + dd],
                     Wff[(size_t)(h * D_ + dd) * D_ + d], s);
        W2[(size_t)f * HD_ + t] = s;
    } else if (b < 644) {                         // wscore: 128x8
        const int idx = (b - 640) * 256 + t;      // [0,1024)
        const int f = idx >> 3, c8 = idx & 7;
        const int h = c8 & 3;
        const float* a = (c8 < 4) ? atti : attj;
        float s = 0.f;
        for (int d = 0; d < D_; ++d)
            s = fmaf(Wlin[(size_t)f * HD_ + h * D_ + d], a[h * D_ + d], s);
        wscore[idx] = s;
    } else if (b < 707) {                         // semb: 2000x8
        const int idx = (b - 644) * 256 + t;      // [0,16128)
        const int i = idx >> 3, c8 = idx & 7;
        if (i < N_) {
            const int h = c8 & 3;
            const float* a = (c8 < 4) ? attei : attej;
            float s = 0.f;
            for (int d = 0; d < D_; ++d)
                s = fmaf(emb[(size_t)i * D_ + d], a[h * D_ + d], s);
            semb[idx] = s;
        }
    } else {                                      // bias2 + zero BN stat accumulators
        if (t < D_) {
            float s = bff[t];
            for (int c = 0; c < HD_; ++c)
                s = fmaf(biasg[c], Wff[(size_t)c * D_ + t], s);
            bias2[t] = s;
            S2[t] = 0.0; SS2[t] = 0.0;
        }
        for (int idx = t; idx < NREP_ * D_; idx += 256) {
            S1R[idx] = 0.0; SS1R[idx] = 0.0;
        }
    }
}

// ---------------------------------------------------------------- cos tile GEMM: 16 rows x 256 cols / block
__global__ __launch_bounds__(256) void k_cos(const float* __restrict__ emb,
                                             const float* __restrict__ embT,
                                             const float* __restrict__ nrm,
                                             float* __restrict__ cosm) {
    const int t    = threadIdx.x;
    const int i0   = blockIdx.y * 16;
    const int r0   = (t >> 6) * 4;
    const int lane = t & 63;
    const int j4   = blockIdx.x * 256 + lane * 4;

    __shared__ float eL[16 * D_];        // 4 KB
    for (int idx = t; idx < 16 * D_; idx += 256)
        eL[idx] = emb[(size_t)i0 * D_ + idx];
    __syncthreads();

    float acc[4][4];
    #pragma unroll
    for (int r = 0; r < 4; ++r)
        #pragma unroll
        for (int cc = 0; cc < 4; ++cc) acc[r][cc] = 0.f;

    for (int k4 = 0; k4 < D_; k4 += 4) {
        float es[4][4];
        #pragma unroll
        for (int r = 0; r < 4; ++r) {
            float4 ev = *(const float4*)&eL[(r0 + r) * D_ + k4];   // wave-uniform broadcast
            es[r][0] = ev.x; es[r][1] = ev.y; es[r][2] = ev.z; es[r][3] = ev.w;
        }
        #pragma unroll
        for (int kk = 0; kk < 4; ++kk) {
            float4 b = *(const float4*)&embT[(size_t)(k4 + kk) * NP_ + j4];  // coalesced
            #pragma unroll
            for (int r = 0; r < 4; ++r) {
                acc[r][0] = fmaf(es[r][kk], b.x, acc[r][0]);
                acc[r][1] = fmaf(es[r][kk], b.y, acc[r][1]);
                acc[r][2] = fmaf(es[r][kk], b.z, acc[r][2]);
                acc[r][3] = fmaf(es[r][kk], b.w, acc[r][3]);
            }
        }
    }

    float4 nj = *(const float4*)&nrm[j4];   // pad lanes read 1.0
    #pragma unroll
    for (int r = 0; r < 4; ++r) {
        float ni = nrm[i0 + r0 + r];
        float4 o;
        o.x = acc[r][0] / (ni * nj.x);      // same formula/order as before
        o.y = acc[r][1] / (ni * nj.y);
        o.z = acc[r][2] / (ni * nj.z);
        o.w = acc[r][3] / (ni * nj.w);
        *(float4*)&cosm[(size_t)(i0 + r0 + r) * NP_ + j4] = o;
    }
}

// ---------------------------------------------------------------- top-k select: one wave per row, packed u64 keys
__device__ __forceinline__ unsigned long long kmax64(unsigned long long a,
                                                     unsigned long long b) {
    return a > b ? a : b;
}

__global__ __launch_bounds__(256) void k_sel(const float* __restrict__ cosm,
                                             int* __restrict__ topk) {
    const int t    = threadIdx.x;
    const int lane = t & 63;
    const int i    = blockIdx.x * 4 + (t >> 6);
    const float* row = cosm + (size_t)i * NP_;

    // slot s -> j = (s>>2)*256 + lane*4 + (s&3)
    unsigned long long key[32];
    #pragma unroll
    for (int m = 0; m < 8; ++m) {
        float4 b = *(const float4*)&row[m * 256 + lane * 4];
        float vv[4] = {b.x, b.y, b.z, b.w};
        #pragma unroll
        for (int q = 0; q < 4; ++q) {
            const int s = m * 4 + q;
            const int j = m * 256 + lane * 4 + q;
            unsigned int x  = __float_as_uint(vv[q]);
            unsigned int mv = (x & 0x80000000u) ? ~x : (x | 0x80000000u);
            unsigned long long kk =
                ((unsigned long long)mv << 32) | (unsigned int)(NP_ - 1 - j);
            key[s] = (j < N_) ? kk : 0ull;   // pad/killed slots: smallest key
        }
    }

    unsigned long long loc;
    {
        unsigned long long l1[16];
        #pragma unroll
        for (int s = 0; s < 16; ++s) l1[s] = kmax64(key[s], key[s + 16]);
        unsigned long long l2[8];
        #pragma unroll
        for (int s = 0; s < 8; ++s) l2[s] = kmax64(l1[s], l1[s + 8]);
        unsigned long long l3[4];
        #pragma unroll
        for (int s = 0; s < 4; ++s) l3[s] = kmax64(l2[s], l2[s + 4]);
        loc = kmax64(kmax64(l3[0], l3[2]), kmax64(l3[1], l3[3]));
    }

    for (int k = 0; k < K_; ++k) {
        unsigned long long w = loc;
        #pragma unroll
        for (int off = 1; off < 64; off <<= 1)
            w = kmax64(w, __shfl_xor(w, off, 64));

        if (lane == 0)
            topk[i * K_ + k] = (NP_ - 1) - (int)(unsigned int)(w & 0xFFFFFFFFu);

        #pragma unroll
        for (int s = 0; s < 32; ++s)
            if (key[s] == w) key[s] = 0ull;
        {
            unsigned long long l1[16];
            #pragma unroll
            for (int s = 0; s < 16; ++s) l1[s] = kmax64(key[s], key[s + 16]);
            unsigned long long l2[8];
            #pragma unroll
            for (int s = 0; s < 8; ++s) l2[s] = kmax64(l1[s], l1[s + 8]);
            unsigned long long l3[4];
            #pragma unroll
            for (int s = 0; s < 4; ++s) l3[s] = kmax64(l2[s], l2[s + 4]);
            loc = kmax64(kmax64(l3[0], l3[2]), kmax64(l3[1], l3[3]));
        }
    }
}

// ---------------------------------------------------------------- k_lin: yh = x@W2 + scores (32 nodes/block)
#define XS_ 132
__global__ __launch_bounds__(256) void k_lin(const float* __restrict__ x,
                                             const float* __restrict__ W2,
                                             const float* __restrict__ wscore,
                                             const float* __restrict__ semb,
                                             float* __restrict__ yh,
                                             float* __restrict__ si,
                                             float* __restrict__ sj) {
    const int t    = threadIdx.x;
    const int n0   = blockIdx.x * 32;     // 1000 blocks
    const int r0   = (t >> 6) * 8;        // wave's 8 rows
    const int lane = t & 63;
    const int c4   = lane * 4;

    __shared__ float xL[32 * XS_];        // 16.9 KB (padded rows)
    __shared__ float wsL[F_ * 8];         // 4 KB

    for (int idx = t; idx < 32 * F_; idx += 256)
        xL[(idx >> 7) * XS_ + (idx & 127)] = x[(size_t)n0 * F_ + idx];
    for (int idx = t; idx < F_ * 8; idx += 256)
        wsL[idx] = wscore[idx];
    __syncthreads();

    float acc[8][4];
    #pragma unroll
    for (int r = 0; r < 8; ++r)
        #pragma unroll
        for (int cc = 0; cc < 4; ++cc) acc[r][cc] = 0.f;

    for (int k4 = 0; k4 < F_; k4 += 4) {
        float xs[8][4];
        #pragma unroll
        for (int r = 0; r < 8; ++r) {
            float4 xv = *(const float4*)&xL[(r0 + r) * XS_ + k4];  // uniform broadcast
            xs[r][0] = xv.x; xs[r][1] = xv.y; xs[r][2] = xv.z; xs[r][3] = xv.w;
        }
        #pragma unroll
        for (int kk = 0; kk < 4; ++kk) {
            float4 w = *(const float4*)&W2[(size_t)(k4 + kk) * HD_ + c4];  // coalesced
            #pragma unroll
            for (int r = 0; r < 8; ++r) {
                acc[r][0] = fmaf(xs[r][kk], w.x, acc[r][0]);
                acc[r][1] = fmaf(xs[r][kk], w.y, acc[r][1]);
                acc[r][2] = fmaf(xs[r][kk], w.z, acc[r][2]);
                acc[r][3] = fmaf(xs[r][kk], w.w, acc[r][3]);
            }
        }
    }

    #pragma unroll
    for (int r = 0; r < 8; ++r) {
        float4 o; o.x = acc[r][0]; o.y = acc[r][1]; o.z = acc[r][2]; o.w = acc[r][3];
        *(float4*)&yh[(size_t)(n0 + r0 + r) * HD_ + c4] = o;
    }

    // scores: 32 rows x 8 (c8: 0-3 = si heads, 4-7 = sj heads) = 256 tasks, 1/thread
    {
        const int row = t >> 3, c8 = t & 7;
        float s = 0.f;
        for (int k4 = 0; k4 < F_; k4 += 4) {
            float4 xv = *(const float4*)&xL[row * XS_ + k4];  // 8 rows -> 8 banks
            s = fmaf(xv.x, wsL[(k4 + 0) * 8 + c8], s);
            s = fmaf(xv.y, wsL[(k4 + 1) * 8 + c8], s);
            s = fmaf(xv.z, wsL[(k4 + 2) * 8 + c8], s);
            s = fmaf(xv.w, wsL[(k4 + 3) * 8 + c8], s);
        }
        const int n = n0 + row;
        const int i = n % N_;
        s += semb[i * 8 + c8];
        if (c8 < 4) si[(size_t)n * H_ + c8]       = s;
        else        sj[(size_t)n * H_ + (c8 - 4)] = s;
    }
}

// ---------------------------------------------------------------- attention: softmax + gather-sum of yh + head-reduce + BN1 stats
// RA_=8 (measured-good gather config); stats -> 16-replica f64 atomics (250/addr).
#define RA_ 8
__global__ __launch_bounds__(256) void k_attn(const float* __restrict__ yh,
                                              const float* __restrict__ si,
                                              const float* __restrict__ sj,
                                              const int* __restrict__ topk,
                                              const float* __restrict__ bias2,
                                              float* __restrict__ out2,
                                              double* __restrict__ S1R,
                                              double* __restrict__ SS1R) {
    const int t   = threadIdx.x;
    const int nwg = BN_ / RA_;                            // 4000, %8==0
    const int swz = (blockIdx.x & 7) * (nwg >> 3) + (blockIdx.x >> 3);  // bijective
    const int n0  = swz * RA_;
    __shared__ int   srcL[RA_][21];
    __shared__ float wA[RA_][H_][21];
    __shared__ float oL[RA_][D_];         // staged out2 values for BN1 stats (2 KB)

    if (t < RA_ * 21) {                   // 8 nodes * 21 edges
        const int r = t / 21, e = t % 21;
        const int n = n0 + r;
        const int i = n % N_;
        const int b = n / N_;
        int s; bool dead = false;
        if (e < K_) { int kk = topk[i * K_ + e]; s = b * N_ + kk; dead = (kk == i); }
        else        { s = n; }
        srcL[r][e] = s;
        #pragma unroll
        for (int h = 0; h < H_; ++h) {
            float a = si[(size_t)n * H_ + h] + sj[(size_t)s * H_ + h];
            a = a > 0.f ? a : 0.2f * a;   // leaky_relu(0.2)
            if (dead) a = -1e30f;         // removed self-loop (after lrelu, as in ref)
            wA[r][h][e] = a;
        }
    }
    __syncthreads();

    if (t < RA_ * H_) {                   // softmax over 21 edges, per (node, head)
        const int r = t >> 2, h = t & 3;
        float m = -3e38f;
        for (int e = 0; e < 21; ++e) m = fmaxf(m, wA[r][h][e]);
        float sum = 0.f;
        for (int e = 0; e < 21; ++e) { float ex = expf(wA[r][h][e] - m); wA[r][h][e] = ex; sum += ex; }
        float inv = 1.f / (sum + 1e-16f);
        for (int e = 0; e < 21; ++e) wA[r][h][e] *= inv;
    }
    __syncthreads();

    {   // gather-weighted sum of yh rows, then reduce over heads via shfl
        const int g = t >> 6, lane = t & 63, c4 = lane * 4, h = lane >> 4;
        #pragma unroll
        for (int rr = 0; rr < 2; ++rr) {
            const int r = g * 2 + rr;
            float a0 = 0.f, a1 = 0.f, a2 = 0.f, a3 = 0.f;
            for (int e = 0; e < 21; ++e) {
                float wv = wA[r][h][e];
                float4 yv = *(const float4*)&yh[(size_t)srcL[r][e] * HD_ + c4];
                a0 = fmaf(wv, yv.x, a0); a1 = fmaf(wv, yv.y, a1);
                a2 = fmaf(wv, yv.z, a2); a3 = fmaf(wv, yv.w, a3);
            }
            // sum the 4 head-lanes {l, l^16, l^32, l^48}
            a0 += __shfl_xor(a0, 16); a0 += __shfl_xor(a0, 32);
            a1 += __shfl_xor(a1, 16); a1 += __shfl_xor(a1, 32);
            a2 += __shfl_xor(a2, 16); a2 += __shfl_xor(a2, 32);
            a3 += __shfl_xor(a3, 16); a3 += __shfl_xor(a3, 32);
            if (lane < 16) {
                float4 b2 = *(const float4*)&bias2[lane * 4];
                float4 o; o.x = a0 + b2.x; o.y = a1 + b2.y;
                          o.z = a2 + b2.z; o.w = a3 + b2.w;
                *(float4*)&out2[(size_t)(n0 + r) * D_ + lane * 4] = o;
                *(float4*)&oL[r][lane * 4] = o;
            }
        }
    }
    __syncthreads();

    if (t < D_) {                         // BN1 partial stats: channel t over 8 rows
        double s = 0.0, ss = 0.0;
        #pragma unroll
        for (int r = 0; r < RA_; ++r) {
            double v = (double)oL[r][t];
            s += v; ss += v * v;
        }
        const int rep = (blockIdx.x & (NREP_ - 1)) * D_;
        atomicAdd(&S1R[rep + t], s);
        atomicAdd(&SS1R[rep + t], ss);
    }
}

// ---------------------------------------------------------------- BN1 apply + *emb + BN2 stats
__global__ __launch_bounds__(256) void k_bn1(const float* __restrict__ out2,
                                             const float* __restrict__ emb,
                                             const double* __restrict__ S1R,
                                             const double* __restrict__ SS1R,
                                             const float* __restrict__ g1,
                                             const float* __restrict__ b1,
                                             float* __restrict__ hb,
                                             double* __restrict__ S2,
                                             double* __restrict__ SS2) {
    const int t = threadIdx.x;
    __shared__ float scale[64], shift[64];
    if (t < 64) {
        double sum = 0.0, ssum = 0.0;
        #pragma unroll
        for (int r = 0; r < NREP_; ++r) {
            sum  += S1R[r * D_ + t];
            ssum += SS1R[r * D_ + t];
        }
        double mu  = sum / (double)BN_;
        double var = ssum / (double)BN_ - mu * mu;
        float rstd = rsqrtf((float)var + EPS_);
        float sc   = rstd * g1[t];
        scale[t] = sc;
        shift[t] = b1[t] - (float)mu * sc;
    }
    __syncthreads();
    const int d = t & 63;
    double s = 0.0, ss = 0.0;
    const int total = BN_ * D_;
    for (int idx = blockIdx.x * 256 + t; idx < total; idx += gridDim.x * 256) {
        float v = out2[idx];
        v = v * scale[d] + shift[d];
        v = fmaxf(v, 0.f);
        int n = idx >> 6;          // node index
        int i = n % N_;
        v *= emb[(size_t)i * D_ + d];
        hb[idx] = v;
        s += v; ss += (double)v * v;
    }
    __shared__ double sb[256], ssb[256];
    sb[t] = s; ssb[t] = ss;
    __syncthreads();
    if (t < 64) {
        double a = sb[t] + sb[t + 64] + sb[t + 128] + sb[t + 192];
        double b = ssb[t] + ssb[t + 64] + ssb[t + 128] + ssb[t + 192];
        atomicAdd(&S2[t], a);
        atomicAdd(&SS2[t], b);
    }
}

// ---------------------------------------------------------------- BN2 apply + out = h@W_out + b_out (16 nodes/block)
__global__ __launch_bounds__(256) void k_out(const float* __restrict__ hb,
                                             const double* __restrict__ S2,
                                             const double* __restrict__ SS2,
                                             const float* __restrict__ g2,
                                             const float* __restrict__ b2,
                                             const float* __restrict__ Wout,
                                             const float* __restrict__ bout,
                                             float* __restrict__ out) {
    const int t  = threadIdx.x;
    const int n0 = blockIdx.x * 16;
    __shared__ float scale[64], shift[64];
    __shared__ float hL[16 * D_];
    if (t < 64) {
        double mu  = S2[t] / (double)BN_;
        double var = SS2[t] / (double)BN_ - mu * mu;
        float rstd = rsqrtf((float)var + EPS_);
        float sc   = rstd * g2[t];
        scale[t] = sc;
        shift[t] = b2[t] - (float)mu * sc;
    }
    __syncthreads();
    for (int idx = t; idx < 16 * D_; idx += 256) {
        float v = hb[(size_t)n0 * D_ + idx];
        int d = idx & 63;
        v = fmaxf(v * scale[d] + shift[d], 0.f);
        hL[idx] = v;
    }
    __syncthreads();
    if (t < OW_) {
        float acc[16];
        #pragma unroll
        for (int r = 0; r < 16; ++r) acc[r] = 0.f;
        for (int d4 = 0; d4 < D_; d4 += 4) {
            float hs[16][4];
            #pragma unroll
            for (int r = 0; r < 16; ++r) {
                float4 hv = *(const float4*)&hL[r * D_ + d4];   // uniform b128 broadcast
                hs[r][0] = hv.x; hs[r][1] = hv.y; hs[r][2] = hv.z; hs[r][3] = hv.w;
            }
            #pragma unroll
            for (int kk = 0; kk < 4; ++kk) {
                float w = Wout[(size_t)(d4 + kk) * OW_ + t];
                #pragma unroll
                for (int r = 0; r < 16; ++r) acc[r] = fmaf(hs[r][kk], w, acc[r]);
            }
        }
        float bo = bout[t];
        #pragma unroll
        for (int r = 0; r < 16; ++r) out[(size_t)(n0 + r) * OW_ + t] = acc[r] + bo;
    }
}

// ---------------------------------------------------------------- launch
extern "C" void kernel_launch(void* const* d_in, const int* in_sizes, int n_in,
                              void* d_out, int out_size, void* d_ws, size_t ws_size,
                              hipStream_t stream) {
    const float* data  = (const float*)d_in[0];
    const float* emb   = (const float*)d_in[1];
    const float* Wlin  = (const float*)d_in[2];
    const float* atti  = (const float*)d_in[3];
    const float* attj  = (const float*)d_in[4];
    const float* attei = (const float*)d_in[5];
    const float* attej = (const float*)d_in[6];
    const float* biasg = (const float*)d_in[7];
    const float* Wff   = (const float*)d_in[8];
    const float* bff   = (const float*)d_in[9];
    const float* g1    = (const float*)d_in[10];
    const float* b1    = (const float*)d_in[11];
    const float* g2    = (const float*)d_in[12];
    const float* b2    = (const float*)d_in[13];
    const float* Wout  = (const float*)d_in[14];
    const float* bout  = (const float*)d_in[15];
    float* out = (float*)d_out;

    char* w = (char*)d_ws;
    size_t off = 0;
    auto alloc = [&](size_t bytes) -> void* {
        void* p = w + off;
        off += (bytes + 255) & ~(size_t)255;
        return p;
    };
    float*  nrm    = (float*) alloc((size_t)NP_ * sizeof(float));        // padded
    int*    topk   = (int*)   alloc((size_t)N_ * K_ * sizeof(int));
    float*  bias2  = (float*) alloc((size_t)D_ * sizeof(float));
    float*  W2     = (float*) alloc((size_t)F_ * HD_ * sizeof(float));   // 131 KB
    float*  wscore = (float*) alloc((size_t)F_ * 8 * sizeof(float));     // 4 KB
    float*  semb   = (float*) alloc((size_t)N_ * 8 * sizeof(float));     // 64 KB
    // union region: {embT, cosm} live only during topk phase; yh reuses it after
    float*  yh   = (float*) alloc((size_t)BN_ * HD_ * sizeof(float));    // 32.8 MB
    float*  embT = yh;                                                   // 0.5 MB
    float*  cosm = yh + (size_t)D_ * NP_;                                // 16.4 MB
    float*  si   = (float*) alloc((size_t)BN_ * H_ * sizeof(float));
    float*  sj   = (float*) alloc((size_t)BN_ * H_ * sizeof(float));
    float*  out2 = (float*) alloc((size_t)BN_ * D_ * sizeof(float));     // 8.2 MB
    float*  hb   = (float*) alloc((size_t)BN_ * D_ * sizeof(float));     // 8.2 MB
    double* S1R  = (double*)alloc((size_t)NREP_ * D_ * sizeof(double));  // 8 KB
    double* SS1R = (double*)alloc((size_t)NREP_ * D_ * sizeof(double));  // 8 KB
    double* S2   = (double*)alloc(64 * sizeof(double));
    double* SS2  = (double*)alloc(64 * sizeof(double));

    hipLaunchKernelGGL(k_prep,  dim3(708),          dim3(256), 0, stream,
                       emb, Wlin, atti, attj, attei, attej, biasg, Wff, bff,
                       nrm, embT, W2, wscore, semb, bias2, S1R, SS1R, S2, SS2);
    hipLaunchKernelGGL(k_cos,   dim3(NP_/256, N_/16), dim3(256), 0, stream,
                       emb, embT, nrm, cosm);
    hipLaunchKernelGGL(k_sel,   dim3(N_/4),          dim3(256), 0, stream, cosm, topk);
    hipLaunchKernelGGL(k_lin,   dim3(BN_ / 32),      dim3(256), 0, stream,
                       data, W2, wscore, semb, yh, si, sj);
    hipLaunchKernelGGL(k_attn,  dim3(BN_ / RA_),     dim3(256), 0, stream,
                       yh, si, sj, topk, bias2, out2, S1R, SS1R);
    hipLaunchKernelGGL(k_bn1,   dim3(512),           dim3(256), 0, stream,
                       out2, emb, S1R, SS1R, g1, b1, hb, S2, SS2);
    hipLaunchKernelGGL(k_out,   dim3(BN_ / 16),      dim3(256), 0, stream,
                       hb, S2, SS2, g2, b2, Wout, bout, out);
}